// Round 7
// baseline (686.566 us; speedup 1.0000x reference)
//
#include <hip/hip_runtime.h>
#include <hip/hip_bf16.h>
#include <stdint.h>

// ---------------------------------------------------------------------------
// PytorchLlamaSDPA: GQA attention (64 q-heads, 8 kv-heads, S=KV=2048, D=128)
// + additive mask (s,t) + softmax + PV + output projection (8192x8192^T).
// bf16 MFMA, fp32 softmax/accum.
// Attention: 8-warp 32x32 swapped-QK^T, K+V LDS dbuf, in-register P exchange.
// GEMM: 128x128 tile, BK=32, 4-buffer LDS, counted-vmcnt pipeline (never
// drains to 0 in the main loop), raw s_barrier, setprio around MFMA.
// ---------------------------------------------------------------------------

typedef __bf16 bf16;
typedef __attribute__((ext_vector_type(8))) __bf16 bf16x8;
typedef __attribute__((ext_vector_type(4))) __bf16 bf16x4;
typedef __attribute__((ext_vector_type(4))) float f32x4;
typedef __attribute__((ext_vector_type(16))) float f32x16;
typedef __attribute__((ext_vector_type(4))) unsigned int u32x4;

#define N_HEADS 64
#define N_KVH   8
#define HDIM    128
#define SEQ     2048
#define KVL     2048
#define DIM     8192

__device__ __forceinline__ void gload16(const void* g, void* l) {
  __builtin_amdgcn_global_load_lds((const __attribute__((address_space(1))) void*)g,
                                   (__attribute__((address_space(3))) void*)l,
                                   16, 0, 0);
}

// pack two floats to one u32 of two bf16 (lo in bits 15:0) - pure bit ops
__device__ __forceinline__ unsigned pack2(float lo, float hi) {
  union { bf16 h; unsigned short u; } a, b;
  a.h = (bf16)lo; b.h = (bf16)hi;
  return ((unsigned)b.u << 16) | (unsigned)a.u;
}

// cross-half exchange: r0 = lane<32 ? a : partner(b); r1 = lane<32 ? partner(a) : b
__device__ __forceinline__ void exch(unsigned a, unsigned b, bool hi, unsigned& r0, unsigned& r1) {
  unsigned sa = (unsigned)__shfl_xor((int)a, 32);
  unsigned sb = (unsigned)__shfl_xor((int)b, 32);
  r0 = hi ? sb : a;
  r1 = hi ? b  : sa;
}

// Build two PV B-operand fragments (kv-slices of 16) from one 32-kv P strip.
// p[r] holds P at kv = (r&3) + 8*(r>>2) + 4*ihi for this lane's q = lane&31.
__device__ __forceinline__ void buildfrags(const float (&p)[16], bool hi, bf16x8& f0, bf16x8& f1) {
  unsigned pk0 = pack2(p[0],  p[1]),  pk1 = pack2(p[2],  p[3]);
  unsigned pk2 = pack2(p[4],  p[5]),  pk3 = pack2(p[6],  p[7]);
  unsigned pk4 = pack2(p[8],  p[9]),  pk5 = pack2(p[10], p[11]);
  unsigned pk6 = pack2(p[12], p[13]), pk7 = pack2(p[14], p[15]);
  unsigned a0, a1, b0, b1, c0, c1, d0, d1;
  exch(pk0, pk2, hi, a0, a1);
  exch(pk1, pk3, hi, b0, b1);
  exch(pk4, pk6, hi, c0, c1);
  exch(pk5, pk7, hi, d0, d1);
  u32x4 w0 = { a0, b0, a1, b1 };
  u32x4 w1 = { c0, d0, c1, d1 };
  f0 = __builtin_bit_cast(bf16x8, w0);
  f1 = __builtin_bit_cast(bf16x8, w1);
}

// --------------------------- fp32 -> bf16 (flat) ---------------------------
__global__ void cvt_f32_bf16(const float* __restrict__ in, bf16* __restrict__ out, int n4) {
  int i = blockIdx.x * blockDim.x + threadIdx.x;
  int stride = gridDim.x * blockDim.x;
  for (; i < n4; i += stride) {
    float4 v = ((const float4*)in)[i];
    bf16x4 o = { (bf16)v.x, (bf16)v.y, (bf16)v.z, (bf16)v.w };
    *(bf16x4*)(out + (long)i * 4) = o;
  }
}

// ------------------- values (kh,t,d) -> bf16 V^T (kh,d,t) ------------------
__global__ void cvt_vT_kernel(const float* __restrict__ v, bf16* __restrict__ vT) {
  __shared__ bf16 tile[64][132];
  const int tid = threadIdx.x;
  const int kh = blockIdx.x >> 5;
  const int t0 = (blockIdx.x & 31) << 6;
  const float* src = v + ((long)kh * KVL + t0) * HDIM;
#pragma unroll
  for (int it = 0; it < 8; ++it) {
    int q = it * 256 + tid;
    int r = q >> 5;
    int c4 = (q & 31) << 2;
    float4 val = *(const float4*)(src + (long)r * HDIM + c4);
    bf16x4 o = { (bf16)val.x, (bf16)val.y, (bf16)val.z, (bf16)val.w };
    *(bf16x4*)&tile[r][c4] = o;
  }
  __syncthreads();
  const int t = tid & 63;
  const int dbase = tid >> 6;
#pragma unroll
  for (int it = 0; it < 32; ++it) {
    int d = it * 4 + dbase;
    vT[((long)kh * HDIM + d) * KVL + t0 + t] = tile[t][d];
  }
}

// ------------------------------- attention ---------------------------------
// (unchanged from round 6 - passed at ~260us)
__global__ __launch_bounds__(512, 2) void attn_kernel(
    const bf16* __restrict__ qB, const bf16* __restrict__ kB,
    const bf16* __restrict__ vT, const float* __restrict__ mask,
    bf16* __restrict__ attnB)
{
  __shared__ __align__(16) char lds[65536];

  const int tid  = threadIdx.x;
  const int lane = tid & 63;
  const int w    = tid >> 6;
  const bool hi  = (lane >> 5) != 0;
  const int ihi  = lane >> 5;
  const int l31  = lane & 31;

  const int bid = blockIdx.x;
  const int h   = bid >> 3;
  const int q0b = (bid & 7) << 8;
  const int kh  = h >> 3;

  // ---- stage Q [256 rows][256B], chunk-swizzled; uses whole 64KB ----
#pragma unroll
  for (int rnd = 0; rnd < 8; ++rnd) {
    int row = rnd * 32 + w * 4 + (lane >> 4);
    int cg  = (lane & 15) ^ (row & 7);
    const bf16* g = qB + (((long)(q0b + row) * N_HEADS + h) << 7) + (cg << 3);
    gload16(g, lds + rnd * 8192 + w * 1024);
  }
  __syncthreads();

  bf16x8 qf[8];
  {
    int qrow = (w << 5) + l31;
    const char* qr = lds + qrow * 256;
#pragma unroll
    for (int s = 0; s < 8; ++s)
      qf[s] = *(const bf16x8*)(qr + ((((s << 1) | ihi) ^ (qrow & 7)) << 4));
  }
  __syncthreads();

  // ---- stage K/V tile 0 into buffer 0 ----
  {
#pragma unroll
    for (int rnd = 0; rnd < 2; ++rnd) {
      int row = rnd * 32 + w * 4 + (lane >> 4);
      int cg  = (lane & 15) ^ (row & 7);
      const bf16* g = kB + (((long)(kh * KVL + row)) << 7) + (cg << 3);
      gload16(g, lds + rnd * 8192 + w * 1024);
    }
#pragma unroll
    for (int rnd = 0; rnd < 2; ++rnd) {
      int row = rnd * 64 + w * 8 + (lane >> 3);
      int cg  = (lane & 7) ^ (row & 7);
      const bf16* g = vT + ((long)(kh * HDIM + row) * KVL) + (cg << 3);
      gload16(g, lds + 32768 + rnd * 8192 + w * 1024);
    }
  }
  __syncthreads();

  const float scale = 0.08838834764831845f;  // 1/sqrt(128)
  const float* mrow = mask + (size_t)(q0b + (w << 5) + l31) * KVL + (ihi << 2);

  f32x16 acc[4];
#pragma unroll
  for (int dt = 0; dt < 4; ++dt) acc[dt] = {};
  float m_run = -1e30f, l_run = 0.f;

  for (int kt = 0; kt < KVL / 64; ++kt) {
    const int cur = kt & 1;
    const int kv0 = kt << 6;

    if (kt < KVL / 64 - 1) {
      const int kv0n = kv0 + 64;
#pragma unroll
      for (int rnd = 0; rnd < 2; ++rnd) {
        int row = rnd * 32 + w * 4 + (lane >> 4);
        int cg  = (lane & 15) ^ (row & 7);
        const bf16* g = kB + (((long)(kh * KVL + kv0n + row)) << 7) + (cg << 3);
        gload16(g, lds + (cur ^ 1) * 16384 + rnd * 8192 + w * 1024);
      }
#pragma unroll
      for (int rnd = 0; rnd < 2; ++rnd) {
        int row = rnd * 64 + w * 8 + (lane >> 3);
        int cg  = (lane & 7) ^ (row & 7);
        const bf16* g = vT + ((long)(kh * HDIM + row) * KVL) + kv0n + (cg << 3);
        gload16(g, lds + 32768 + (cur ^ 1) * 16384 + rnd * 8192 + w * 1024);
      }
    }

    const float* mrt = mrow + kv0;
    f32x4 mk0[4], mk1[4];
#pragma unroll
    for (int rq = 0; rq < 4; ++rq) {
      mk0[rq] = *(const f32x4*)(mrt + (rq << 3));
      mk1[rq] = *(const f32x4*)(mrt + 32 + (rq << 3));
    }

    const char* kb = lds + cur * 16384;
    f32x16 s0 = {}, s1 = {};
    const int kr0 = l31, kr1 = 32 + l31;
#pragma unroll
    for (int s = 0; s < 8; ++s) {
      bf16x8 kf0 = *(const bf16x8*)(kb + kr0 * 256 + ((((s << 1) | ihi) ^ (kr0 & 7)) << 4));
      s0 = __builtin_amdgcn_mfma_f32_32x32x16_bf16(kf0, qf[s], s0, 0, 0, 0);
      bf16x8 kf1 = *(const bf16x8*)(kb + kr1 * 256 + ((((s << 1) | ihi) ^ (kr1 & 7)) << 4));
      s1 = __builtin_amdgcn_mfma_f32_32x32x16_bf16(kf1, qf[s], s1, 0, 0, 0);
    }

    float p0[16], p1[16];
#pragma unroll
    for (int rq = 0; rq < 4; ++rq) {
#pragma unroll
      for (int j = 0; j < 4; ++j) {
        p0[rq * 4 + j] = s0[rq * 4 + j] * scale + mk0[rq][j];
        p1[rq * 4 + j] = s1[rq * 4 + j] * scale + mk1[rq][j];
      }
    }

    float mx = p0[0];
#pragma unroll
    for (int i = 1; i < 16; ++i) mx = fmaxf(mx, p0[i]);
#pragma unroll
    for (int i = 0; i < 16; ++i) mx = fmaxf(mx, p1[i]);
    mx = fmaxf(mx, __shfl_xor(mx, 32));
    float nm = fmaxf(m_run, mx);
    float al = __expf(m_run - nm);
    m_run = nm;
    float ps = 0.f;
#pragma unroll
    for (int i = 0; i < 16; ++i) { p0[i] = __expf(p0[i] - nm); ps += p0[i]; }
#pragma unroll
    for (int i = 0; i < 16; ++i) { p1[i] = __expf(p1[i] - nm); ps += p1[i]; }
    ps += __shfl_xor(ps, 32);
    l_run = l_run * al + ps;
#pragma unroll
    for (int dt = 0; dt < 4; ++dt) acc[dt] *= al;

    bf16x8 pfrag[4];
    buildfrags(p0, hi, pfrag[0], pfrag[1]);
    buildfrags(p1, hi, pfrag[2], pfrag[3]);

    const char* vb = lds + 32768 + cur * 16384;
#pragma unroll
    for (int dt = 0; dt < 4; ++dt) {
      const int vrow = (dt << 5) + l31;
      const char* vrp = vb + vrow * 128;
#pragma unroll
      for (int ks = 0; ks < 4; ++ks) {
        bf16x8 vf = *(const bf16x8*)(vrp + ((((ks << 1) | ihi) ^ (vrow & 7)) << 4));
        acc[dt] = __builtin_amdgcn_mfma_f32_32x32x16_bf16(vf, pfrag[ks], acc[dt], 0, 0, 0);
      }
    }
    __syncthreads();
  }

  // ---- epilogue: normalize, LDS transpose, coalesced bf16x8 stores ----
  const float linv = 1.0f / l_run;
  char* ep = lds + (w << 13);
#pragma unroll
  for (int dt = 0; dt < 4; ++dt) {
#pragma unroll
    for (int r = 0; r < 16; ++r) {
      int d = (dt << 5) + (r & 3) + ((r >> 2) << 3) + (ihi << 2);
      int byte = l31 * 256 + (((d >> 3) ^ (l31 & 7)) << 4) + ((d & 7) << 1);
      *(bf16*)(ep + byte) = (bf16)(acc[dt][r] * linv);
    }
  }
  __syncthreads();
  const size_t obase = (size_t)(q0b + (w << 5)) * DIM + h * HDIM;
#pragma unroll
  for (int i = 0; i < 8; ++i) {
    int row = (i << 2) + (lane >> 4);
    int cp  = lane & 15;
    int c   = cp ^ (row & 7);
    bf16x8 ov = *(const bf16x8*)(ep + row * 256 + (cp << 4));
    *(bf16x8*)(attnB + obase + (size_t)row * DIM + (c << 3)) = ov;
  }
}

// ------------------------------ projection GEMM ----------------------------
// C[2048x8192] = A[2048x8192] * B[8192x8192]^T. 128x128 tile, BK=32,
// 4 LDS buffers (4 x (A 8KB + B 8KB) = 64KB), staging 3 tiles ahead with
// counted vmcnt (8 = 2 tiles in flight across each barrier; never 0 in the
// main loop). Raw s_barrier (no compiler vmcnt(0) drain). 64B rows,
// slot key (r + r>>2)&3 keeps worst-case LDS aliasing at 2-way (free).
#define GKEY(r) (((r) + ((r) >> 2)) & 3)

__global__ __launch_bounds__(256, 2) void gemm_bt(
    const bf16* __restrict__ A, const bf16* __restrict__ B, float* __restrict__ C)
{
  __shared__ __align__(16) char lds[65536];
  const int tid = threadIdx.x;
  const int lane = tid & 63;
  const int w = tid >> 6;

  const int swz = (blockIdx.x & 7) * 128 + (blockIdx.x >> 3);
  const int m0 = (swz >> 6) << 7;
  const int n0 = (swz & 63) << 7;
  const int wr = (w >> 1) << 6;
  const int wc = (w & 1) << 6;

  const int ra0 = tid >> 2;        // staging row, round 0 (0..63)
  const int ra1 = 64 + ra0;        // staging row, round 1
  const int sc  = tid & 3;         // staging slot
  const int c0  = (sc ^ GKEY(ra0)) << 3;   // source k-chunk (elems) round 0
  const int c1  = (sc ^ GKEY(ra1)) << 3;   // source k-chunk round 1

  const bf16* gA0 = A + (long)(m0 + ra0) * DIM + c0;
  const bf16* gA1 = A + (long)(m0 + ra1) * DIM + c1;
  const bf16* gB0 = B + (long)(n0 + ra0) * DIM + c0;
  const bf16* gB1 = B + (long)(n0 + ra1) * DIM + c1;

  f32x4 acc[4][4];
#pragma unroll
  for (int i = 0; i < 4; ++i)
#pragma unroll
    for (int j = 0; j < 4; ++j) acc[i][j] = { 0.f, 0.f, 0.f, 0.f };

  auto STAGE = [&](int kt, int buf) {
    const long ko = (long)kt << 5;
    char* base = lds + buf * 16384 + w * 1024;
    gload16(gA0 + ko, base);
    gload16(gA1 + ko, base + 4096);
    gload16(gB0 + ko, base + 8192);
    gload16(gB1 + ko, base + 12288);
  };

  const int g = lane >> 4;
  auto COMPUTE = [&](int buf) {
    const char* ab = lds + buf * 16384;
    const char* bb = ab + 8192;
    bf16x8 af[4], bfr[4];
#pragma unroll
    for (int i = 0; i < 4; ++i) {
      int m = wr + i * 16 + (lane & 15);
      af[i] = *(const bf16x8*)(ab + m * 64 + ((g ^ GKEY(m)) << 4));
      int n = wc + i * 16 + (lane & 15);
      bfr[i] = *(const bf16x8*)(bb + n * 64 + ((g ^ GKEY(n)) << 4));
    }
    __builtin_amdgcn_s_setprio(1);
#pragma unroll
    for (int i = 0; i < 4; ++i)
#pragma unroll
      for (int j = 0; j < 4; ++j)
        acc[i][j] = __builtin_amdgcn_mfma_f32_16x16x32_bf16(af[i], bfr[j], acc[i][j], 0, 0, 0);
    __builtin_amdgcn_s_setprio(0);
  };

  // prologue: 3 tiles in flight
  STAGE(0, 0);
  STAGE(1, 1);
  STAGE(2, 2);

  // main loop: tiles 0..251 (256 total, BK=32)
#pragma unroll 4
  for (int t = 0; t < 252; ++t) {
    asm volatile("s_waitcnt vmcnt(8)" ::: "memory");   // tile t landed (mine)
    __builtin_amdgcn_s_barrier();                      // block-wide: tile t in LDS,
    __builtin_amdgcn_sched_barrier(0);                 // prior reads retired
    STAGE(t + 3, (t + 3) & 3);
    COMPUTE(t & 3);
  }
  // t = 252 (stage final tile 255)
  asm volatile("s_waitcnt vmcnt(8)" ::: "memory");
  __builtin_amdgcn_s_barrier();
  __builtin_amdgcn_sched_barrier(0);
  STAGE(255, 3);
  COMPUTE(0);
  // t = 253
  asm volatile("s_waitcnt vmcnt(8)" ::: "memory");
  __builtin_amdgcn_s_barrier();
  __builtin_amdgcn_sched_barrier(0);
  COMPUTE(1);
  // t = 254
  asm volatile("s_waitcnt vmcnt(4)" ::: "memory");
  __builtin_amdgcn_s_barrier();
  __builtin_amdgcn_sched_barrier(0);
  COMPUTE(2);
  // t = 255
  asm volatile("s_waitcnt vmcnt(0)" ::: "memory");
  __builtin_amdgcn_s_barrier();
  __builtin_amdgcn_sched_barrier(0);
  COMPUTE(3);

#pragma unroll
  for (int i = 0; i < 4; ++i) {
#pragma unroll
    for (int r = 0; r < 4; ++r) {
      float* cp = C + (long)(m0 + wr + i * 16 + ((lane >> 4) << 2) + r) * DIM + n0 + wc + (lane & 15);
#pragma unroll
      for (int j = 0; j < 4; ++j)
        cp[j * 16] = acc[i][j][r];
    }
  }
}

// ------------------------------- launcher ----------------------------------
extern "C" void kernel_launch(void* const* d_in, const int* in_sizes, int n_in,
                              void* d_out, int out_size, void* d_ws, size_t ws_size,
                              hipStream_t stream) {
  const float* xq     = (const float*)d_in[0];
  const float* keys   = (const float*)d_in[1];
  const float* values = (const float*)d_in[2];
  const float* mask   = (const float*)d_in[3];
  const float* wo     = (const float*)d_in[4];
  float* out = (float*)d_out;
  char* ws = (char*)d_ws;

  bf16* woB = (bf16*)ws;                                   // 128 MB
  bf16* qB  = (bf16*)(ws + 134217728ull);                  //  32 MB
  bf16* kB  = (bf16*)(ws + 134217728ull + 33554432ull);    //   4 MB
  bf16* vT  = (bf16*)(ws + 134217728ull + 37748736ull);    //   4 MB
  bf16* aB  = (bf16*)(ws + 134217728ull + 41943040ull);    //  32 MB

  cvt_f32_bf16<<<dim3(2048), dim3(256), 0, stream>>>(wo, woB, 16777216);
  cvt_f32_bf16<<<dim3(1024), dim3(256), 0, stream>>>(xq, qB, 4194304);
  cvt_f32_bf16<<<dim3(256),  dim3(256), 0, stream>>>(keys, kB, 524288);
  cvt_vT_kernel<<<dim3(256), dim3(256), 0, stream>>>(values, vT);
  attn_kernel<<<dim3(512),   dim3(512), 0, stream>>>(qB, kB, vT, mask, aB);
  gemm_bt<<<dim3(1024),      dim3(256), 0, stream>>>(aB, woB, out);
}

// Round 8
// 605.022 us; speedup vs baseline: 1.1348x; 1.1348x over previous
//
#include <hip/hip_runtime.h>
#include <hip/hip_bf16.h>
#include <stdint.h>

// ---------------------------------------------------------------------------
// PytorchLlamaSDPA: GQA attention (64 q-heads, 8 kv-heads, S=KV=2048, D=128)
// + additive mask (s,t) + softmax + PV + output projection (8192x8192^T).
// bf16 MFMA, fp32 softmax/accum.
// Attention: 8-warp 32x32 swapped-QK^T, K+V LDS dbuf, in-register P exchange.
// GEMM: 256x256 tile, 8 waves, BK=32, 4 LDS slots (128KB), prefetch depth 3,
// counted vmcnt(8) (never drains in main loop), one raw s_barrier per tile.
// ---------------------------------------------------------------------------

typedef __bf16 bf16;
typedef __attribute__((ext_vector_type(8))) __bf16 bf16x8;
typedef __attribute__((ext_vector_type(4))) __bf16 bf16x4;
typedef __attribute__((ext_vector_type(4))) float f32x4;
typedef __attribute__((ext_vector_type(16))) float f32x16;
typedef __attribute__((ext_vector_type(4))) unsigned int u32x4;

#define N_HEADS 64
#define N_KVH   8
#define HDIM    128
#define SEQ     2048
#define KVL     2048
#define DIM     8192

__device__ __forceinline__ void gload16(const void* g, void* l) {
  __builtin_amdgcn_global_load_lds((const __attribute__((address_space(1))) void*)g,
                                   (__attribute__((address_space(3))) void*)l,
                                   16, 0, 0);
}

// pack two floats to one u32 of two bf16 (lo in bits 15:0) - pure bit ops
__device__ __forceinline__ unsigned pack2(float lo, float hi) {
  union { bf16 h; unsigned short u; } a, b;
  a.h = (bf16)lo; b.h = (bf16)hi;
  return ((unsigned)b.u << 16) | (unsigned)a.u;
}

// cross-half exchange: r0 = lane<32 ? a : partner(b); r1 = lane<32 ? partner(a) : b
__device__ __forceinline__ void exch(unsigned a, unsigned b, bool hi, unsigned& r0, unsigned& r1) {
  unsigned sa = (unsigned)__shfl_xor((int)a, 32);
  unsigned sb = (unsigned)__shfl_xor((int)b, 32);
  r0 = hi ? sb : a;
  r1 = hi ? b  : sa;
}

// Build two PV B-operand fragments (kv-slices of 16) from one 32-kv P strip.
__device__ __forceinline__ void buildfrags(const float (&p)[16], bool hi, bf16x8& f0, bf16x8& f1) {
  unsigned pk0 = pack2(p[0],  p[1]),  pk1 = pack2(p[2],  p[3]);
  unsigned pk2 = pack2(p[4],  p[5]),  pk3 = pack2(p[6],  p[7]);
  unsigned pk4 = pack2(p[8],  p[9]),  pk5 = pack2(p[10], p[11]);
  unsigned pk6 = pack2(p[12], p[13]), pk7 = pack2(p[14], p[15]);
  unsigned a0, a1, b0, b1, c0, c1, d0, d1;
  exch(pk0, pk2, hi, a0, a1);
  exch(pk1, pk3, hi, b0, b1);
  exch(pk4, pk6, hi, c0, c1);
  exch(pk5, pk7, hi, d0, d1);
  u32x4 w0 = { a0, b0, a1, b1 };
  u32x4 w1 = { c0, d0, c1, d1 };
  f0 = __builtin_bit_cast(bf16x8, w0);
  f1 = __builtin_bit_cast(bf16x8, w1);
}

// --------------------------- fp32 -> bf16 (flat) ---------------------------
__global__ void cvt_f32_bf16(const float* __restrict__ in, bf16* __restrict__ out, int n4) {
  int i = blockIdx.x * blockDim.x + threadIdx.x;
  int stride = gridDim.x * blockDim.x;
  for (; i < n4; i += stride) {
    float4 v = ((const float4*)in)[i];
    bf16x4 o = { (bf16)v.x, (bf16)v.y, (bf16)v.z, (bf16)v.w };
    *(bf16x4*)(out + (long)i * 4) = o;
  }
}

// ------------------- values (kh,t,d) -> bf16 V^T (kh,d,t) ------------------
__global__ void cvt_vT_kernel(const float* __restrict__ v, bf16* __restrict__ vT) {
  __shared__ bf16 tile[64][132];
  const int tid = threadIdx.x;
  const int kh = blockIdx.x >> 5;
  const int t0 = (blockIdx.x & 31) << 6;
  const float* src = v + ((long)kh * KVL + t0) * HDIM;
#pragma unroll
  for (int it = 0; it < 8; ++it) {
    int q = it * 256 + tid;
    int r = q >> 5;
    int c4 = (q & 31) << 2;
    float4 val = *(const float4*)(src + (long)r * HDIM + c4);
    bf16x4 o = { (bf16)val.x, (bf16)val.y, (bf16)val.z, (bf16)val.w };
    *(bf16x4*)&tile[r][c4] = o;
  }
  __syncthreads();
  const int t = tid & 63;
  const int dbase = tid >> 6;
#pragma unroll
  for (int it = 0; it < 32; ++it) {
    int d = it * 4 + dbase;
    vT[((long)kh * HDIM + d) * KVL + t0 + t] = tile[t][d];
  }
}

// ------------------------------- attention ---------------------------------
// (unchanged from round 6 - ~250us)
__global__ __launch_bounds__(512, 2) void attn_kernel(
    const bf16* __restrict__ qB, const bf16* __restrict__ kB,
    const bf16* __restrict__ vT, const float* __restrict__ mask,
    bf16* __restrict__ attnB)
{
  __shared__ __align__(16) char lds[65536];

  const int tid  = threadIdx.x;
  const int lane = tid & 63;
  const int w    = tid >> 6;
  const bool hi  = (lane >> 5) != 0;
  const int ihi  = lane >> 5;
  const int l31  = lane & 31;

  const int bid = blockIdx.x;
  const int h   = bid >> 3;
  const int q0b = (bid & 7) << 8;
  const int kh  = h >> 3;

#pragma unroll
  for (int rnd = 0; rnd < 8; ++rnd) {
    int row = rnd * 32 + w * 4 + (lane >> 4);
    int cg  = (lane & 15) ^ (row & 7);
    const bf16* g = qB + (((long)(q0b + row) * N_HEADS + h) << 7) + (cg << 3);
    gload16(g, lds + rnd * 8192 + w * 1024);
  }
  __syncthreads();

  bf16x8 qf[8];
  {
    int qrow = (w << 5) + l31;
    const char* qr = lds + qrow * 256;
#pragma unroll
    for (int s = 0; s < 8; ++s)
      qf[s] = *(const bf16x8*)(qr + ((((s << 1) | ihi) ^ (qrow & 7)) << 4));
  }
  __syncthreads();

  {
#pragma unroll
    for (int rnd = 0; rnd < 2; ++rnd) {
      int row = rnd * 32 + w * 4 + (lane >> 4);
      int cg  = (lane & 15) ^ (row & 7);
      const bf16* g = kB + (((long)(kh * KVL + row)) << 7) + (cg << 3);
      gload16(g, lds + rnd * 8192 + w * 1024);
    }
#pragma unroll
    for (int rnd = 0; rnd < 2; ++rnd) {
      int row = rnd * 64 + w * 8 + (lane >> 3);
      int cg  = (lane & 7) ^ (row & 7);
      const bf16* g = vT + ((long)(kh * HDIM + row) * KVL) + (cg << 3);
      gload16(g, lds + 32768 + rnd * 8192 + w * 1024);
    }
  }
  __syncthreads();

  const float scale = 0.08838834764831845f;  // 1/sqrt(128)
  const float* mrow = mask + (size_t)(q0b + (w << 5) + l31) * KVL + (ihi << 2);

  f32x16 acc[4];
#pragma unroll
  for (int dt = 0; dt < 4; ++dt) acc[dt] = {};
  float m_run = -1e30f, l_run = 0.f;

  for (int kt = 0; kt < KVL / 64; ++kt) {
    const int cur = kt & 1;
    const int kv0 = kt << 6;

    if (kt < KVL / 64 - 1) {
      const int kv0n = kv0 + 64;
#pragma unroll
      for (int rnd = 0; rnd < 2; ++rnd) {
        int row = rnd * 32 + w * 4 + (lane >> 4);
        int cg  = (lane & 15) ^ (row & 7);
        const bf16* g = kB + (((long)(kh * KVL + kv0n + row)) << 7) + (cg << 3);
        gload16(g, lds + (cur ^ 1) * 16384 + rnd * 8192 + w * 1024);
      }
#pragma unroll
      for (int rnd = 0; rnd < 2; ++rnd) {
        int row = rnd * 64 + w * 8 + (lane >> 3);
        int cg  = (lane & 7) ^ (row & 7);
        const bf16* g = vT + ((long)(kh * HDIM + row) * KVL) + kv0n + (cg << 3);
        gload16(g, lds + 32768 + (cur ^ 1) * 16384 + rnd * 8192 + w * 1024);
      }
    }

    const float* mrt = mrow + kv0;
    f32x4 mk0[4], mk1[4];
#pragma unroll
    for (int rq = 0; rq < 4; ++rq) {
      mk0[rq] = *(const f32x4*)(mrt + (rq << 3));
      mk1[rq] = *(const f32x4*)(mrt + 32 + (rq << 3));
    }

    const char* kb = lds + cur * 16384;
    f32x16 s0 = {}, s1 = {};
    const int kr0 = l31, kr1 = 32 + l31;
#pragma unroll
    for (int s = 0; s < 8; ++s) {
      bf16x8 kf0 = *(const bf16x8*)(kb + kr0 * 256 + ((((s << 1) | ihi) ^ (kr0 & 7)) << 4));
      s0 = __builtin_amdgcn_mfma_f32_32x32x16_bf16(kf0, qf[s], s0, 0, 0, 0);
      bf16x8 kf1 = *(const bf16x8*)(kb + kr1 * 256 + ((((s << 1) | ihi) ^ (kr1 & 7)) << 4));
      s1 = __builtin_amdgcn_mfma_f32_32x32x16_bf16(kf1, qf[s], s1, 0, 0, 0);
    }

    float p0[16], p1[16];
#pragma unroll
    for (int rq = 0; rq < 4; ++rq) {
#pragma unroll
      for (int j = 0; j < 4; ++j) {
        p0[rq * 4 + j] = s0[rq * 4 + j] * scale + mk0[rq][j];
        p1[rq * 4 + j] = s1[rq * 4 + j] * scale + mk1[rq][j];
      }
    }

    float mx = p0[0];
#pragma unroll
    for (int i = 1; i < 16; ++i) mx = fmaxf(mx, p0[i]);
#pragma unroll
    for (int i = 0; i < 16; ++i) mx = fmaxf(mx, p1[i]);
    mx = fmaxf(mx, __shfl_xor(mx, 32));
    float nm = fmaxf(m_run, mx);
    float al = __expf(m_run - nm);
    m_run = nm;
    float ps = 0.f;
#pragma unroll
    for (int i = 0; i < 16; ++i) { p0[i] = __expf(p0[i] - nm); ps += p0[i]; }
#pragma unroll
    for (int i = 0; i < 16; ++i) { p1[i] = __expf(p1[i] - nm); ps += p1[i]; }
    ps += __shfl_xor(ps, 32);
    l_run = l_run * al + ps;
#pragma unroll
    for (int dt = 0; dt < 4; ++dt) acc[dt] *= al;

    bf16x8 pfrag[4];
    buildfrags(p0, hi, pfrag[0], pfrag[1]);
    buildfrags(p1, hi, pfrag[2], pfrag[3]);

    const char* vb = lds + 32768 + cur * 16384;
#pragma unroll
    for (int dt = 0; dt < 4; ++dt) {
      const int vrow = (dt << 5) + l31;
      const char* vrp = vb + vrow * 128;
#pragma unroll
      for (int ks = 0; ks < 4; ++ks) {
        bf16x8 vf = *(const bf16x8*)(vrp + ((((ks << 1) | ihi) ^ (vrow & 7)) << 4));
        acc[dt] = __builtin_amdgcn_mfma_f32_32x32x16_bf16(vf, pfrag[ks], acc[dt], 0, 0, 0);
      }
    }
    __syncthreads();
  }

  const float linv = 1.0f / l_run;
  char* ep = lds + (w << 13);
#pragma unroll
  for (int dt = 0; dt < 4; ++dt) {
#pragma unroll
    for (int r = 0; r < 16; ++r) {
      int d = (dt << 5) + (r & 3) + ((r >> 2) << 3) + (ihi << 2);
      int byte = l31 * 256 + (((d >> 3) ^ (l31 & 7)) << 4) + ((d & 7) << 1);
      *(bf16*)(ep + byte) = (bf16)(acc[dt][r] * linv);
    }
  }
  __syncthreads();
  const size_t obase = (size_t)(q0b + (w << 5)) * DIM + h * HDIM;
#pragma unroll
  for (int i = 0; i < 8; ++i) {
    int row = (i << 2) + (lane >> 4);
    int cp  = lane & 15;
    int c   = cp ^ (row & 7);
    bf16x8 ov = *(const bf16x8*)(ep + row * 256 + (cp << 4));
    *(bf16x8*)(attnB + obase + (size_t)row * DIM + (c << 3)) = ov;
  }
}

// ------------------------------ projection GEMM ----------------------------
// C[2048x8192] = A[2048x8192] * B[8192x8192]^T. 256x256 tile, 512 threads
// (8 waves = 2m x 4n), BK=32, 4 LDS slots of 32KB (A 16KB + B 16KB) = 128KB.
// Prefetch depth 3 tiles; per tile: vmcnt(8) -> s_barrier -> STAGE(t+3) ->
// COMPUTE(t). 64B rows, chunk key (row>>1)&3 -> worst-case 2-way (free).
__global__ __launch_bounds__(512, 2) void gemm_bt(
    const bf16* __restrict__ A, const bf16* __restrict__ B, float* __restrict__ C)
{
  __shared__ __align__(16) char lds[131072];
  const int tid  = threadIdx.x;
  const int lane = tid & 63;
  const int w    = tid >> 6;
  const int wm   = w >> 2;       // 0..1
  const int wn   = w & 3;        // 0..3

  const int bid = blockIdx.x;
  const int m0  = (bid & 7) << 8;    // 8 m-tiles: one per XCD (A-panel L2-resident)
  const int n0  = (bid >> 3) << 8;   // 32 n-tiles

  // staging source: thread -> (row = tid>>2 [+128 for round 1], chunk = tid&3)
  const int srow = tid >> 2;                 // 0..127
  const int skey = (srow >> 1) & 3;          // key(row) == key(row+128)
  const int sch  = (tid & 3) ^ skey;         // pre-swizzled source chunk
  const bf16* gA0 = A + (long)(m0 + srow) * DIM + (sch << 3);
  const bf16* gA1 = gA0 + (long)128 * DIM;
  const bf16* gB0 = B + (long)(n0 + srow) * DIM + (sch << 3);
  const bf16* gB1 = gB0 + (long)128 * DIM;

  f32x4 acc[8][4];
#pragma unroll
  for (int i = 0; i < 8; ++i)
#pragma unroll
    for (int j = 0; j < 4; ++j) acc[i][j] = { 0.f, 0.f, 0.f, 0.f };

  auto STAGE = [&](int kt) {
    const long ko = (long)kt << 5;
    char* s = lds + (kt & 3) * 32768 + (w << 10);
    gload16(gA0 + ko, s);
    gload16(gA1 + ko, s + 8192);
    gload16(gB0 + ko, s + 16384);
    gload16(gB1 + ko, s + 24576);
  };

  const int g = lane >> 4;
  auto COMPUTE = [&](int slot) {
    const char* ab = lds + slot * 32768;
    const char* bb = ab + 16384;
    bf16x8 af[8], bfr[4];
#pragma unroll
    for (int i = 0; i < 8; ++i) {
      int m = (wm << 7) + (i << 4) + (lane & 15);
      af[i] = *(const bf16x8*)(ab + m * 64 + ((g ^ ((m >> 1) & 3)) << 4));
    }
#pragma unroll
    for (int j = 0; j < 4; ++j) {
      int n = (wn << 6) + (j << 4) + (lane & 15);
      bfr[j] = *(const bf16x8*)(bb + n * 64 + ((g ^ ((n >> 1) & 3)) << 4));
    }
    __builtin_amdgcn_s_setprio(1);
#pragma unroll
    for (int i = 0; i < 8; ++i)
#pragma unroll
      for (int j = 0; j < 4; ++j)
        acc[i][j] = __builtin_amdgcn_mfma_f32_16x16x32_bf16(af[i], bfr[j], acc[i][j], 0, 0, 0);
    __builtin_amdgcn_s_setprio(0);
  };

  // prologue: 3 tiles in flight (12 loads/thread)
  STAGE(0);
  STAGE(1);
  STAGE(2);

  // main loop: 256 K-tiles of 32
#pragma unroll 4
  for (int t = 0; t < 252; ++t) {
    asm volatile("s_waitcnt vmcnt(8)" ::: "memory");  // tile t landed (all waves after barrier)
    __builtin_amdgcn_s_barrier();
    STAGE(t + 3);
    COMPUTE(t & 3);
  }
  // t = 252: stage last tile
  asm volatile("s_waitcnt vmcnt(8)" ::: "memory");
  __builtin_amdgcn_s_barrier();
  STAGE(255);
  COMPUTE(0);
  // t = 253
  asm volatile("s_waitcnt vmcnt(8)" ::: "memory");
  __builtin_amdgcn_s_barrier();
  COMPUTE(1);
  // t = 254
  asm volatile("s_waitcnt vmcnt(4)" ::: "memory");
  __builtin_amdgcn_s_barrier();
  COMPUTE(2);
  // t = 255
  asm volatile("s_waitcnt vmcnt(0)" ::: "memory");
  __builtin_amdgcn_s_barrier();
  COMPUTE(3);

  // epilogue: C fp32 stores
#pragma unroll
  for (int i = 0; i < 8; ++i) {
#pragma unroll
    for (int rr = 0; rr < 4; ++rr) {
      float* cp = C + (long)(m0 + (wm << 7) + (i << 4) + ((lane >> 4) << 2) + rr) * DIM
                    + n0 + (wn << 6) + (lane & 15);
#pragma unroll
      for (int j = 0; j < 4; ++j)
        cp[j * 16] = acc[i][j][rr];
    }
  }
}

// ------------------------------- launcher ----------------------------------
extern "C" void kernel_launch(void* const* d_in, const int* in_sizes, int n_in,
                              void* d_out, int out_size, void* d_ws, size_t ws_size,
                              hipStream_t stream) {
  const float* xq     = (const float*)d_in[0];
  const float* keys   = (const float*)d_in[1];
  const float* values = (const float*)d_in[2];
  const float* mask   = (const float*)d_in[3];
  const float* wo     = (const float*)d_in[4];
  float* out = (float*)d_out;
  char* ws = (char*)d_ws;

  bf16* woB = (bf16*)ws;                                   // 128 MB
  bf16* qB  = (bf16*)(ws + 134217728ull);                  //  32 MB
  bf16* kB  = (bf16*)(ws + 134217728ull + 33554432ull);    //   4 MB
  bf16* vT  = (bf16*)(ws + 134217728ull + 37748736ull);    //   4 MB
  bf16* aB  = (bf16*)(ws + 134217728ull + 41943040ull);    //  32 MB

  cvt_f32_bf16<<<dim3(2048), dim3(256), 0, stream>>>(wo, woB, 16777216);
  cvt_f32_bf16<<<dim3(1024), dim3(256), 0, stream>>>(xq, qB, 4194304);
  cvt_f32_bf16<<<dim3(256),  dim3(256), 0, stream>>>(keys, kB, 524288);
  cvt_vT_kernel<<<dim3(256), dim3(256), 0, stream>>>(values, vT);
  attn_kernel<<<dim3(512),   dim3(512), 0, stream>>>(qB, kB, vT, mask, aB);
  gemm_bt<<<dim3(256),       dim3(512), 0, stream>>>(aB, woB, out);
}

// Round 9
// 552.208 us; speedup vs baseline: 1.2433x; 1.0956x over previous
//
#include <hip/hip_runtime.h>
#include <hip/hip_bf16.h>
#include <stdint.h>

// ---------------------------------------------------------------------------
// PytorchLlamaSDPA: GQA attention (64 q-heads, 8 kv-heads, S=KV=2048, D=128)
// + additive mask (s,t) + softmax + PV + output projection (8192x8192^T).
// bf16 MFMA, fp32 softmax/accum.
// Attention: 8-warp 32x32 swapped-QK^T, K+V LDS dbuf, in-register P exchange,
//            defer-max (THR=8), setprio around MFMA clusters.
// GEMM: 256x256 tile, 8 waves, BK=32, 4 LDS slots (128KB), prefetch depth 3,
// counted vmcnt(8); XCD-co-located B-panel mapping (8 blocks/panel per XCD).
// ---------------------------------------------------------------------------

typedef __bf16 bf16;
typedef __attribute__((ext_vector_type(8))) __bf16 bf16x8;
typedef __attribute__((ext_vector_type(4))) __bf16 bf16x4;
typedef __attribute__((ext_vector_type(4))) float f32x4;
typedef __attribute__((ext_vector_type(16))) float f32x16;
typedef __attribute__((ext_vector_type(4))) unsigned int u32x4;

#define N_HEADS 64
#define N_KVH   8
#define HDIM    128
#define SEQ     2048
#define KVL     2048
#define DIM     8192

__device__ __forceinline__ void gload16(const void* g, void* l) {
  __builtin_amdgcn_global_load_lds((const __attribute__((address_space(1))) void*)g,
                                   (__attribute__((address_space(3))) void*)l,
                                   16, 0, 0);
}

// pack two floats to one u32 of two bf16 (lo in bits 15:0) - pure bit ops
__device__ __forceinline__ unsigned pack2(float lo, float hi) {
  union { bf16 h; unsigned short u; } a, b;
  a.h = (bf16)lo; b.h = (bf16)hi;
  return ((unsigned)b.u << 16) | (unsigned)a.u;
}

// cross-half exchange: r0 = lane<32 ? a : partner(b); r1 = lane<32 ? partner(a) : b
__device__ __forceinline__ void exch(unsigned a, unsigned b, bool hi, unsigned& r0, unsigned& r1) {
  unsigned sa = (unsigned)__shfl_xor((int)a, 32);
  unsigned sb = (unsigned)__shfl_xor((int)b, 32);
  r0 = hi ? sb : a;
  r1 = hi ? b  : sa;
}

// Build two PV B-operand fragments (kv-slices of 16) from one 32-kv P strip.
__device__ __forceinline__ void buildfrags(const float (&p)[16], bool hi, bf16x8& f0, bf16x8& f1) {
  unsigned pk0 = pack2(p[0],  p[1]),  pk1 = pack2(p[2],  p[3]);
  unsigned pk2 = pack2(p[4],  p[5]),  pk3 = pack2(p[6],  p[7]);
  unsigned pk4 = pack2(p[8],  p[9]),  pk5 = pack2(p[10], p[11]);
  unsigned pk6 = pack2(p[12], p[13]), pk7 = pack2(p[14], p[15]);
  unsigned a0, a1, b0, b1, c0, c1, d0, d1;
  exch(pk0, pk2, hi, a0, a1);
  exch(pk1, pk3, hi, b0, b1);
  exch(pk4, pk6, hi, c0, c1);
  exch(pk5, pk7, hi, d0, d1);
  u32x4 w0 = { a0, b0, a1, b1 };
  u32x4 w1 = { c0, d0, c1, d1 };
  f0 = __builtin_bit_cast(bf16x8, w0);
  f1 = __builtin_bit_cast(bf16x8, w1);
}

// --------------------------- fp32 -> bf16 (flat) ---------------------------
__global__ void cvt_f32_bf16(const float* __restrict__ in, bf16* __restrict__ out, int n4) {
  int i = blockIdx.x * blockDim.x + threadIdx.x;
  int stride = gridDim.x * blockDim.x;
  for (; i < n4; i += stride) {
    float4 v = ((const float4*)in)[i];
    bf16x4 o = { (bf16)v.x, (bf16)v.y, (bf16)v.z, (bf16)v.w };
    *(bf16x4*)(out + (long)i * 4) = o;
  }
}

// ------------------- values (kh,t,d) -> bf16 V^T (kh,d,t) ------------------
__global__ void cvt_vT_kernel(const float* __restrict__ v, bf16* __restrict__ vT) {
  __shared__ bf16 tile[64][132];
  const int tid = threadIdx.x;
  const int kh = blockIdx.x >> 5;
  const int t0 = (blockIdx.x & 31) << 6;
  const float* src = v + ((long)kh * KVL + t0) * HDIM;
#pragma unroll
  for (int it = 0; it < 8; ++it) {
    int q = it * 256 + tid;
    int r = q >> 5;
    int c4 = (q & 31) << 2;
    float4 val = *(const float4*)(src + (long)r * HDIM + c4);
    bf16x4 o = { (bf16)val.x, (bf16)val.y, (bf16)val.z, (bf16)val.w };
    *(bf16x4*)&tile[r][c4] = o;
  }
  __syncthreads();
  const int t = tid & 63;
  const int dbase = tid >> 6;
#pragma unroll
  for (int it = 0; it < 32; ++it) {
    int d = it * 4 + dbase;
    vT[((long)kh * HDIM + d) * KVL + t0 + t] = tile[t][d];
  }
}

// ------------------------------- attention ---------------------------------
__global__ __launch_bounds__(512, 2) void attn_kernel(
    const bf16* __restrict__ qB, const bf16* __restrict__ kB,
    const bf16* __restrict__ vT, const float* __restrict__ mask,
    bf16* __restrict__ attnB)
{
  __shared__ __align__(16) char lds[65536];

  const int tid  = threadIdx.x;
  const int lane = tid & 63;
  const int w    = tid >> 6;
  const bool hi  = (lane >> 5) != 0;
  const int ihi  = lane >> 5;
  const int l31  = lane & 31;

  const int bid = blockIdx.x;
  const int h   = bid >> 3;
  const int q0b = (bid & 7) << 8;
  const int kh  = h >> 3;

#pragma unroll
  for (int rnd = 0; rnd < 8; ++rnd) {
    int row = rnd * 32 + w * 4 + (lane >> 4);
    int cg  = (lane & 15) ^ (row & 7);
    const bf16* g = qB + (((long)(q0b + row) * N_HEADS + h) << 7) + (cg << 3);
    gload16(g, lds + rnd * 8192 + w * 1024);
  }
  __syncthreads();

  bf16x8 qf[8];
  {
    int qrow = (w << 5) + l31;
    const char* qr = lds + qrow * 256;
#pragma unroll
    for (int s = 0; s < 8; ++s)
      qf[s] = *(const bf16x8*)(qr + ((((s << 1) | ihi) ^ (qrow & 7)) << 4));
  }
  __syncthreads();

  {
#pragma unroll
    for (int rnd = 0; rnd < 2; ++rnd) {
      int row = rnd * 32 + w * 4 + (lane >> 4);
      int cg  = (lane & 15) ^ (row & 7);
      const bf16* g = kB + (((long)(kh * KVL + row)) << 7) + (cg << 3);
      gload16(g, lds + rnd * 8192 + w * 1024);
    }
#pragma unroll
    for (int rnd = 0; rnd < 2; ++rnd) {
      int row = rnd * 64 + w * 8 + (lane >> 3);
      int cg  = (lane & 7) ^ (row & 7);
      const bf16* g = vT + ((long)(kh * HDIM + row) * KVL) + (cg << 3);
      gload16(g, lds + 32768 + rnd * 8192 + w * 1024);
    }
  }
  __syncthreads();

  const float scale = 0.08838834764831845f;  // 1/sqrt(128)
  const float* mrow = mask + (size_t)(q0b + (w << 5) + l31) * KVL + (ihi << 2);

  f32x16 acc[4];
#pragma unroll
  for (int dt = 0; dt < 4; ++dt) acc[dt] = {};
  float m_run = -1e30f, l_run = 0.f;

  for (int kt = 0; kt < KVL / 64; ++kt) {
    const int cur = kt & 1;
    const int kv0 = kt << 6;

    if (kt < KVL / 64 - 1) {
      const int kv0n = kv0 + 64;
#pragma unroll
      for (int rnd = 0; rnd < 2; ++rnd) {
        int row = rnd * 32 + w * 4 + (lane >> 4);
        int cg  = (lane & 15) ^ (row & 7);
        const bf16* g = kB + (((long)(kh * KVL + kv0n + row)) << 7) + (cg << 3);
        gload16(g, lds + (cur ^ 1) * 16384 + rnd * 8192 + w * 1024);
      }
#pragma unroll
      for (int rnd = 0; rnd < 2; ++rnd) {
        int row = rnd * 64 + w * 8 + (lane >> 3);
        int cg  = (lane & 7) ^ (row & 7);
        const bf16* g = vT + ((long)(kh * HDIM + row) * KVL) + kv0n + (cg << 3);
        gload16(g, lds + 32768 + (cur ^ 1) * 16384 + rnd * 8192 + w * 1024);
      }
    }

    const float* mrt = mrow + kv0;
    f32x4 mk0[4], mk1[4];
#pragma unroll
    for (int rq = 0; rq < 4; ++rq) {
      mk0[rq] = *(const f32x4*)(mrt + (rq << 3));
      mk1[rq] = *(const f32x4*)(mrt + 32 + (rq << 3));
    }

    const char* kb = lds + cur * 16384;
    f32x16 s0 = {}, s1 = {};
    const int kr0 = l31, kr1 = 32 + l31;
    __builtin_amdgcn_s_setprio(1);
#pragma unroll
    for (int s = 0; s < 8; ++s) {
      bf16x8 kf0 = *(const bf16x8*)(kb + kr0 * 256 + ((((s << 1) | ihi) ^ (kr0 & 7)) << 4));
      s0 = __builtin_amdgcn_mfma_f32_32x32x16_bf16(kf0, qf[s], s0, 0, 0, 0);
      bf16x8 kf1 = *(const bf16x8*)(kb + kr1 * 256 + ((((s << 1) | ihi) ^ (kr1 & 7)) << 4));
      s1 = __builtin_amdgcn_mfma_f32_32x32x16_bf16(kf1, qf[s], s1, 0, 0, 0);
    }
    __builtin_amdgcn_s_setprio(0);

    float p0[16], p1[16];
#pragma unroll
    for (int rq = 0; rq < 4; ++rq) {
#pragma unroll
      for (int j = 0; j < 4; ++j) {
        p0[rq * 4 + j] = s0[rq * 4 + j] * scale + mk0[rq][j];
        p1[rq * 4 + j] = s1[rq * 4 + j] * scale + mk1[rq][j];
      }
    }

    // ---- online softmax with defer-max (THR=8) ----
    float mx = p0[0];
#pragma unroll
    for (int i = 1; i < 16; ++i) mx = fmaxf(mx, p0[i]);
#pragma unroll
    for (int i = 0; i < 16; ++i) mx = fmaxf(mx, p1[i]);
    mx = fmaxf(mx, __shfl_xor(mx, 32));
    if (!__all((int)(mx - m_run <= 8.0f))) {
      float nm = fmaxf(m_run, mx);
      float al = __expf(m_run - nm);
      m_run = nm;
      l_run *= al;
#pragma unroll
      for (int dt = 0; dt < 4; ++dt) acc[dt] *= al;
    }
    float ps = 0.f;
#pragma unroll
    for (int i = 0; i < 16; ++i) { p0[i] = __expf(p0[i] - m_run); ps += p0[i]; }
#pragma unroll
    for (int i = 0; i < 16; ++i) { p1[i] = __expf(p1[i] - m_run); ps += p1[i]; }
    ps += __shfl_xor(ps, 32);
    l_run += ps;

    bf16x8 pfrag[4];
    buildfrags(p0, hi, pfrag[0], pfrag[1]);
    buildfrags(p1, hi, pfrag[2], pfrag[3]);

    const char* vb = lds + 32768 + cur * 16384;
    __builtin_amdgcn_s_setprio(1);
#pragma unroll
    for (int dt = 0; dt < 4; ++dt) {
      const int vrow = (dt << 5) + l31;
      const char* vrp = vb + vrow * 128;
#pragma unroll
      for (int ks = 0; ks < 4; ++ks) {
        bf16x8 vf = *(const bf16x8*)(vrp + ((((ks << 1) | ihi) ^ (vrow & 7)) << 4));
        acc[dt] = __builtin_amdgcn_mfma_f32_32x32x16_bf16(vf, pfrag[ks], acc[dt], 0, 0, 0);
      }
    }
    __builtin_amdgcn_s_setprio(0);
    __syncthreads();
  }

  const float linv = 1.0f / l_run;
  char* ep = lds + (w << 13);
#pragma unroll
  for (int dt = 0; dt < 4; ++dt) {
#pragma unroll
    for (int r = 0; r < 16; ++r) {
      int d = (dt << 5) + (r & 3) + ((r >> 2) << 3) + (ihi << 2);
      int byte = l31 * 256 + (((d >> 3) ^ (l31 & 7)) << 4) + ((d & 7) << 1);
      *(bf16*)(ep + byte) = (bf16)(acc[dt][r] * linv);
    }
  }
  __syncthreads();
  const size_t obase = (size_t)(q0b + (w << 5)) * DIM + h * HDIM;
#pragma unroll
  for (int i = 0; i < 8; ++i) {
    int row = (i << 2) + (lane >> 4);
    int cp  = lane & 15;
    int c   = cp ^ (row & 7);
    bf16x8 ov = *(const bf16x8*)(ep + row * 256 + (cp << 4));
    *(bf16x8*)(attnB + obase + (size_t)row * DIM + (c << 3)) = ov;
  }
}

// ------------------------------ projection GEMM ----------------------------
// C[2048x8192] = A[2048x8192] * B[8192x8192]^T. 256x256 tile, 512 threads
// (8 waves = 2m x 4n), BK=32, 4 LDS slots of 32KB (A 16KB + B 16KB) = 128KB.
// Prefetch depth 3; per tile: vmcnt(8) -> s_barrier -> STAGE(t+3) -> COMPUTE.
// Block mapping: XCD (= bid&7) owns 4 B n-panels; the 8 blocks sharing each
// B-panel are co-located on one XCD -> B staging hits that XCD's L2.
__global__ __launch_bounds__(512, 2) void gemm_bt(
    const bf16* __restrict__ A, const bf16* __restrict__ B, float* __restrict__ C)
{
  __shared__ __align__(16) char lds[131072];
  const int tid  = threadIdx.x;
  const int lane = tid & 63;
  const int w    = tid >> 6;
  const int wm   = w >> 2;       // 0..1
  const int wn   = w & 3;        // 0..3

  const int bid = blockIdx.x;
  const int m0  = (bid >> 5) << 8;                              // 8 m-panels
  const int n0  = (((bid & 7) << 2) | ((bid >> 3) & 3)) << 8;   // 32 n-panels, XCD-grouped

  // staging source: thread -> (row = tid>>2 [+128 for round 1], chunk = tid&3)
  const int srow = tid >> 2;                 // 0..127
  const int skey = (srow >> 1) & 3;          // key(row) == key(row+128)
  const int sch  = (tid & 3) ^ skey;         // pre-swizzled source chunk
  const bf16* gA0 = A + (long)(m0 + srow) * DIM + (sch << 3);
  const bf16* gA1 = gA0 + (long)128 * DIM;
  const bf16* gB0 = B + (long)(n0 + srow) * DIM + (sch << 3);
  const bf16* gB1 = gB0 + (long)128 * DIM;

  f32x4 acc[8][4];
#pragma unroll
  for (int i = 0; i < 8; ++i)
#pragma unroll
    for (int j = 0; j < 4; ++j) acc[i][j] = { 0.f, 0.f, 0.f, 0.f };

  auto STAGE = [&](int kt) {
    const long ko = (long)kt << 5;
    char* s = lds + (kt & 3) * 32768 + (w << 10);
    gload16(gA0 + ko, s);
    gload16(gA1 + ko, s + 8192);
    gload16(gB0 + ko, s + 16384);
    gload16(gB1 + ko, s + 24576);
  };

  const int g = lane >> 4;
  auto COMPUTE = [&](int slot) {
    const char* ab = lds + slot * 32768;
    const char* bb = ab + 16384;
    bf16x8 af[8], bfr[4];
#pragma unroll
    for (int i = 0; i < 8; ++i) {
      int m = (wm << 7) + (i << 4) + (lane & 15);
      af[i] = *(const bf16x8*)(ab + m * 64 + ((g ^ ((m >> 1) & 3)) << 4));
    }
#pragma unroll
    for (int j = 0; j < 4; ++j) {
      int n = (wn << 6) + (j << 4) + (lane & 15);
      bfr[j] = *(const bf16x8*)(bb + n * 64 + ((g ^ ((n >> 1) & 3)) << 4));
    }
    __builtin_amdgcn_s_setprio(1);
#pragma unroll
    for (int i = 0; i < 8; ++i)
#pragma unroll
      for (int j = 0; j < 4; ++j)
        acc[i][j] = __builtin_amdgcn_mfma_f32_16x16x32_bf16(af[i], bfr[j], acc[i][j], 0, 0, 0);
    __builtin_amdgcn_s_setprio(0);
  };

  // prologue: 3 tiles in flight (12 loads/thread)
  STAGE(0);
  STAGE(1);
  STAGE(2);

  // main loop: 256 K-tiles of 32
#pragma unroll 4
  for (int t = 0; t < 252; ++t) {
    asm volatile("s_waitcnt vmcnt(8)" ::: "memory");
    __builtin_amdgcn_s_barrier();
    STAGE(t + 3);
    COMPUTE(t & 3);
  }
  asm volatile("s_waitcnt vmcnt(8)" ::: "memory");
  __builtin_amdgcn_s_barrier();
  STAGE(255);
  COMPUTE(0);
  asm volatile("s_waitcnt vmcnt(8)" ::: "memory");
  __builtin_amdgcn_s_barrier();
  COMPUTE(1);
  asm volatile("s_waitcnt vmcnt(4)" ::: "memory");
  __builtin_amdgcn_s_barrier();
  COMPUTE(2);
  asm volatile("s_waitcnt vmcnt(0)" ::: "memory");
  __builtin_amdgcn_s_barrier();
  COMPUTE(3);

  // epilogue: C fp32 stores
#pragma unroll
  for (int i = 0; i < 8; ++i) {
#pragma unroll
    for (int rr = 0; rr < 4; ++rr) {
      float* cp = C + (long)(m0 + (wm << 7) + (i << 4) + ((lane >> 4) << 2) + rr) * DIM
                    + n0 + (wn << 6) + (lane & 15);
#pragma unroll
      for (int j = 0; j < 4; ++j)
        cp[j * 16] = acc[i][j][rr];
    }
  }
}

// ------------------------------- launcher ----------------------------------
extern "C" void kernel_launch(void* const* d_in, const int* in_sizes, int n_in,
                              void* d_out, int out_size, void* d_ws, size_t ws_size,
                              hipStream_t stream) {
  const float* xq     = (const float*)d_in[0];
  const float* keys   = (const float*)d_in[1];
  const float* values = (const float*)d_in[2];
  const float* mask   = (const float*)d_in[3];
  const float* wo     = (const float*)d_in[4];
  float* out = (float*)d_out;
  char* ws = (char*)d_ws;

  bf16* woB = (bf16*)ws;                                   // 128 MB
  bf16* qB  = (bf16*)(ws + 134217728ull);                  //  32 MB
  bf16* kB  = (bf16*)(ws + 134217728ull + 33554432ull);    //   4 MB
  bf16* vT  = (bf16*)(ws + 134217728ull + 37748736ull);    //   4 MB
  bf16* aB  = (bf16*)(ws + 134217728ull + 41943040ull);    //  32 MB

  cvt_f32_bf16<<<dim3(2048), dim3(256), 0, stream>>>(wo, woB, 16777216);
  cvt_f32_bf16<<<dim3(1024), dim3(256), 0, stream>>>(xq, qB, 4194304);
  cvt_f32_bf16<<<dim3(256),  dim3(256), 0, stream>>>(keys, kB, 524288);
  cvt_vT_kernel<<<dim3(256), dim3(256), 0, stream>>>(values, vT);
  attn_kernel<<<dim3(512),   dim3(512), 0, stream>>>(qB, kB, vT, mask, aB);
  gemm_bt<<<dim3(256),       dim3(512), 0, stream>>>(aB, woB, out);
}